// Round 13
// baseline (483.258 us; speedup 1.0000x reference)
//
#include <hip/hip_runtime.h>

constexpr int Bn = 65536;
constexpr int Cn = 4096;
constexpr int Dn = 128;
// Pairwise key-err: x-side f16 std ~3.4e-3 (validated at TAU=0.03, 6 sigma);
// c-side single-f16 => same magnitude, independent => sqrt(2) scale
// (0.042) + u32-mask granularity (~2e-3) + headroom => TAU = 0.055.
// Validated: absmax 0.0 at TAU=0.055 in rounds 3, 5, 6, 7, 8, 9, 10, 11.
constexpr float TAU = 0.055f;

typedef _Float16 v8h __attribute__((ext_vector_type(8)));
typedef float v16f __attribute__((ext_vector_type(16)));

#define MFMA16(a, b, c) __builtin_amdgcn_mfma_f32_32x32x16_f16((a), (b), (c), 0, 0, 0)

// ---------------------------------------------------------------------------
// Pack codes into MFMA A-fragment order as SINGLE f16 planes, PRE-SCALED -2.
// Also computes cnorm (fp64) inline, writes a f32 transposed copy codesT[d][c]
// (for the coalesced rescore), zeroes flagcount and the gather done-counter.
// Tile ct (128 tiles, 4608 halves = 9216 B):
//   slice s in [0,8): hi @ ct*4608 + s*512 + l*8
//   slice 8: 3-term f16 split of (cnorm[code] + 512) at k=0,1,2 (lanes l<32);
//            with B=ones at k=0..2 one MFMA makes acc = key+512 directly
//            (+512 keeps keys positive => u32-sortable floats).
// ---------------------------------------------------------------------------
__global__ void pack_codes_kernel(const float* __restrict__ codes,
                                  float* __restrict__ cnorm,
                                  _Float16* __restrict__ pack,
                                  float* __restrict__ codesT,
                                  int* __restrict__ flagcount,
                                  int* __restrict__ done) {
  int tid = blockIdx.x * 256 + threadIdx.x;  // 288 blocks -> 1152 wave-frags
  if (tid == 0) {
    *flagcount = 0;
    *done = 0;
  }
  int f = tid >> 6;
  int l = tid & 63;
  int ct = f / 9, s = f % 9;
  int code = (ct << 5) + (l & 31);
  if (s < 8) {
    int kb = (s << 4) + ((l >> 5) << 3);
    const float* p = codes + (size_t)code * Dn + kb;
    float4 a = ((const float4*)p)[0];
    float4 b = ((const float4*)p)[1];
    float v[8] = {a.x, a.y, a.z, a.w, b.x, b.y, b.z, b.w};
    // f32 transpose for the rescore path (raw values, no -2 scale)
#pragma unroll
    for (int j = 0; j < 8; ++j)
      codesT[(size_t)(kb + j) * Cn + code] = v[j];
    v8h hi;
#pragma unroll
    for (int j = 0; j < 8; ++j) {
      float sv = -2.f * v[j];  // exact scale
      hi[j] = (_Float16)sv;    // single-term f16 (rescore covers the error)
    }
    *(v8h*)(pack + (size_t)ct * 4608 + s * 512 + l * 8) = hi;
  } else {
    v8h a = {0, 0, 0, 0, 0, 0, 0, 0};
    if (l < 32) {
      const float4* p = (const float4*)(codes + (size_t)code * Dn);
      double sd = 0.0;
#pragma unroll
      for (int i = 0; i < Dn / 4; ++i) {
        float4 v = p[i];
        sd += (double)v.x * v.x + (double)v.y * v.y + (double)v.z * v.z +
              (double)v.w * v.w;
      }
      float cn = (float)sd;
      cnorm[code] = cn;
      float c5 = cn + 512.f;
      _Float16 h1 = (_Float16)c5;
      float r1 = c5 - (float)h1;
      _Float16 h2 = (_Float16)r1;
      float r2 = r1 - (float)h2;
      _Float16 h3 = (_Float16)r2;
      a[0] = h1;
      a[1] = h2;
      a[2] = h3;
    }
    *(v8h*)(pack + (size_t)ct * 4608 + 8 * 512 + l * 8) = a;
  }
}

// ---------------------------------------------------------------------------
// Main: REGISTER-DIRECT code-quarter sweep, within-wave software pipeline.
// (FROZEN at the r10 form — structural floor ~89.5us. Five scheduling
// structures (barriered x3, barrier-free, SWP, SGB-pinned) all landed
// 89-107us with MFMA(31)+VALU(35)+L2(21) adding serially; SGB was null.)
// acc[r] = key + 512 (always positive). Branchless epilogue: pack 4-bit r
// into low mantissa bits; pair-merge network gives exact (min, in-tile 2nd,
// idx) in u32 domain (positive keys => u32 order = f32 order).
// C/D 32x32: col = lane&31 = x-row, code-row = (r&3)+8*(r>>2)+4*(lane>>5).
// ---------------------------------------------------------------------------
__launch_bounds__(64, 2)
__global__ void argmin_mfma_kernel(const float* __restrict__ x,
                                   const _Float16* __restrict__ pack,
                                   float* __restrict__ pm1,
                                   float* __restrict__ pm2,
                                   float* __restrict__ pidx) {
  const int l = threadIdx.x;  // 64-thread block = one wave
  const int h = blockIdx.x & 3;
  const int row0 = (blockIdx.x >> 2) * 64;

  // x fragments -> registers (single f16). Rows row0 + tt*32 + (l&31).
  v8h xh[2][8];
#pragma unroll
  for (int tt = 0; tt < 2; ++tt) {
#pragma unroll
    for (int ks = 0; ks < 8; ++ks) {
      int xrow = row0 + tt * 32 + (l & 31);
      int kb = ks * 16 + (l >> 5) * 8;
      const float* xp = x + (size_t)xrow * Dn + kb;
      float4 a = ((const float4*)xp)[0];
      float4 b = ((const float4*)xp)[1];
      float v[8] = {a.x, a.y, a.z, a.w, b.x, b.y, b.z, b.w};
      v8h hh;
#pragma unroll
      for (int j = 0; j < 8; ++j) hh[j] = (_Float16)v[j];
      xh[tt][ks] = hh;
    }
  }

  // B fragment of f16 ones at k=0,1,2 (pairs with the cnorm A-slice).
  v8h bones;
#pragma unroll
  for (int j = 0; j < 8; ++j)
    bones[j] = (l < 32 && j < 3) ? (_Float16)1.0f : (_Float16)0.0f;

  v16f zacc;
#pragma unroll
  for (int i = 0; i < 16; ++i) zacc[i] = 0.f;

  // Cross-tile state in packed-u32 domain (keys positive).
  unsigned umin1[2] = {0xFFFFFFFFu, 0xFFFFFFFFu};
  unsigned umin2[2] = {0xFFFFFFFFu, 0xFFFFFFFFu};
  int idx[2] = {0, 0};

  auto update = [&](const v16f& a, int tt, int codebase) {
    // pack r into low 4 mantissa bits (values then unique; u32 order = f32)
    unsigned b[16];
#pragma unroll
    for (int r = 0; r < 16; ++r)
      b[r] = (__float_as_uint(a[r]) & 0xFFFFFFF0u) | (unsigned)r;
    // pair-merge network: exact (m1, m2) of 16 values.
    // Invariant: (m1,m2) = two smallest seen; merging sorted pair (lo,hi):
    //   m1' = min(m1,lo); m2' = min(min(m2,hi), max(m1,lo))   [exact]
    unsigned m1 = 0xFFFFFFFFu, m2 = 0xFFFFFFFFu;
#pragma unroll
    for (int i = 0; i < 8; ++i) {
      unsigned lo = min(b[2 * i], b[2 * i + 1]);
      unsigned hi = max(b[2 * i], b[2 * i + 1]);
      unsigned mx = max(m1, lo);
      m1 = min(m1, lo);
      m2 = min(min(m2, hi), mx);
    }
    unsigned r1 = m1 & 15u;
    int tidx = codebase + (int)(8 * (r1 >> 2) + (r1 & 3));
    bool lt = m1 < umin1[tt];
    umin2[tt] = lt ? min(umin1[tt], m2) : min(umin2[tt], m1);
    idx[tt] = lt ? tidx : idx[tt];
    umin1[tt] = lt ? m1 : umin1[tt];
  };

  // Lane-fixed base into this quarter's 32 tiles of A-fragments.
  const _Float16* pb = pack + (size_t)(h * 32) * 4608 + l * 8;

  auto loadf = [&](v8h* f, int it) {
    const _Float16* tp = pb + (size_t)it * 4608;
#pragma unroll
    for (int s = 0; s < 8; ++s) f[s] = *(const v8h*)(tp + s * 512);
    f[8] = *(const v8h*)(tp + 8 * 512);  // cnorm slice
  };

  auto mfma_tile = [&](const v8h* f, v16f& a0, v16f& a1) {
    v16f ini = MFMA16(f[8], bones, zacc);  // ini = cnorm+512 (shared)
    a0 = MFMA16(f[0], xh[0][0], ini);
    a1 = MFMA16(f[0], xh[1][0], ini);
#pragma unroll
    for (int s = 1; s < 8; ++s) {
      a0 = MFMA16(f[s], xh[0][s], a0);
      a1 = MFMA16(f[s], xh[1][s], a1);
    }
  };

  auto cb = [&](int t) { return h * 1024 + t * 32 + 4 * (l >> 5); };

  v8h fA[9], fB[9];
  v16f accA0, accA1, accB0, accB1;

  // Pipeline: prologue fills fA(0), fB(1); steady state computes tile t
  // while updating tile t-1 and prefetching tile t+1.
  loadf(fA, 0);
  loadf(fB, 1);
  mfma_tile(fA, accA0, accA1);  // tile 0
  for (int it = 1; it < 31; it += 2) {
    loadf(fA, it + 1);             // prefetch tile it+1
    mfma_tile(fB, accB0, accB1);   // tile it
    update(accA0, 0, cb(it - 1));  // finish tile it-1 (VALU in MFMA shadow)
    update(accA1, 1, cb(it - 1));
    loadf(fB, it + 2);             // prefetch tile it+2 (max 31)
    mfma_tile(fA, accA0, accA1);   // tile it+1
    update(accB0, 0, cb(it));      // finish tile it
    update(accB1, 1, cb(it));
  }
  mfma_tile(fB, accB0, accB1);  // tile 31
  update(accA0, 0, cb(30));
  update(accA1, 1, cb(30));
  update(accB0, 0, cb(31));
  update(accB1, 1, cb(31));

  // Merge lane pair (l, l^32): same x-row, complementary code rows.
#pragma unroll
  for (int tt = 0; tt < 2; ++tt) {
    unsigned o1 = (unsigned)__shfl_xor((int)umin1[tt], 32);
    unsigned o2 = (unsigned)__shfl_xor((int)umin2[tt], 32);
    int oi = __shfl_xor(idx[tt], 32);
    bool sw = (o1 < umin1[tt]) || (o1 == umin1[tt] && oi < idx[tt]);
    unsigned n1 = sw ? o1 : umin1[tt];
    int ni = sw ? oi : idx[tt];
    unsigned big = sw ? umin1[tt] : o1;
    unsigned n2 = min(min(umin2[tt], o2), big);
    if (l < 32) {
      int row = row0 + tt * 32 + l;
      pm1[h * Bn + row] = __uint_as_float(n1 & 0xFFFFFFF0u);
      pm2[h * Bn + row] = __uint_as_float(n2 & 0xFFFFFFF0u);
      pidx[h * Bn + row] = (float)ni;
    }
  }
}

// ---------------------------------------------------------------------------
// Merge the four code-quarter partials; write idxf; flag small-margin rows.
// Exact: global m2 = min(pm2[h*], min_{h != h*} pm1[h]); sequential insert
// keeps that invariant. Ties prefer lower h (= lower code index).
// Flagged rows get a NEGATIVE marker idxf[r] = -(j+1) pointing at packed[j]
// (init'd to ~0 here); rescore atomicMins it and rescore_final resolves it
// BEFORE gather (packed aliases quant rows >=32768 — gather overwrites it,
// so nothing after rescore_final may read packed; r12 crashed on this).
// ---------------------------------------------------------------------------
__global__ void merge_kernel(const float* __restrict__ pm1,
                             const float* __restrict__ pm2,
                             const float* __restrict__ pidx,
                             float* __restrict__ idxf,
                             int* __restrict__ flaglist,
                             int* __restrict__ flagcount,
                             unsigned long long* __restrict__ packed) {
  int r = blockIdx.x * 256 + threadIdx.x;
  float m1 = pm1[r];
  float mw2 = pm2[r];  // pm2 of current winner quarter
  float mi = pidx[r];
  float m2 = 3.4e38f;  // min over losers' pm1
#pragma unroll
  for (int h = 1; h < 4; ++h) {
    float v1 = pm1[h * Bn + r];
    float v2 = pm2[h * Bn + r];
    float vi = pidx[h * Bn + r];
    bool win = v1 < m1;
    m2 = fminf(m2, win ? m1 : v1);
    mw2 = win ? v2 : mw2;
    mi = win ? vi : mi;
    m1 = win ? v1 : m1;
  }
  m2 = fminf(m2, mw2);
  if (m2 - m1 < TAU) {
    int p = atomicAdd(flagcount, 1);
    flaglist[p] = r;
    packed[p] = 0xFFFFFFFFFFFFFFFFull;
    idxf[r] = -(float)(p + 1);  // marker: rescore_final resolves it
  } else {
    idxf[r] = mi;
  }
}

// ---------------------------------------------------------------------------
// Exact fp32 rescore, ROW-BATCHED (8 rows share one codesT pass), result via
// per-row u64 atomicMin: val = (orderU32(key) << 32) | idx. orderU32 is the
// standard sign-flip map (order-preserving for ALL floats incl. negatives),
// so u64 min = lexicographic (key asc, idx asc) min — identical selection to
// the old 4-way quarter merge. Clamped tail duplicates are idempotent.
// Per-(row,code) math IDENTICAL to prior rounds => bit-identical keys.
// ---------------------------------------------------------------------------
__device__ __forceinline__ unsigned orderU32(float f) {
  unsigned u = __float_as_uint(f);
  return (u & 0x80000000u) ? ~u : (u | 0x80000000u);
}

__launch_bounds__(256, 4)
__global__ void rescore_part_kernel(const float* __restrict__ x,
                                    const float* __restrict__ codesT,
                                    const float* __restrict__ cnorm,
                                    const int* __restrict__ flaglist,
                                    const int* __restrict__ flagcount,
                                    unsigned long long* __restrict__ packed) {
  __shared__ __align__(16) float xs[8][Dn];
  __shared__ float wv[4][8];
  __shared__ int wis[4][8];
  const int t = threadIdx.x;
  const int cnt = *flagcount;
  const int nb = (cnt + 7) >> 3;
  const int total = nb * 4;

  for (int wi = blockIdx.x; wi < total; wi += gridDim.x) {
    const int b = wi >> 2;
    const int q = wi & 3;
    __syncthreads();  // xs reuse guard (also orders wv/wis reuse)
    {
      int rr = t >> 5;  // 0..7
      int cc = t & 31;  // 0..31
      int j = min(b * 8 + rr, cnt - 1);
      int r = flaglist[j];
      ((float4*)&xs[rr][0])[cc] = ((const float4*)(x + (size_t)r * Dn))[cc];
    }
    __syncthreads();

    const int c0 = q * 1024 + 4 * t;
    const float* cp = codesT + c0;
    float4 s[8];
#pragma unroll
    for (int r = 0; r < 8; ++r) s[r] = (float4){0.f, 0.f, 0.f, 0.f};
    for (int d = 0; d < Dn; ++d) {
      float4 cv = *(const float4*)(cp + (size_t)d * Cn);
#pragma unroll
      for (int r = 0; r < 8; ++r) {
        float xv = xs[r][d];  // LDS broadcast (uniform addr per r)
        s[r].x = fmaf(cv.x, xv, s[r].x);
        s[r].y = fmaf(cv.y, xv, s[r].y);
        s[r].z = fmaf(cv.z, xv, s[r].z);
        s[r].w = fmaf(cv.w, xv, s[r].w);
      }
    }
    const float cn0 = cnorm[c0], cn1 = cnorm[c0 + 1], cn2 = cnorm[c0 + 2],
                cn3 = cnorm[c0 + 3];
    float bv[8];
    int bi[8];
#pragma unroll
    for (int r = 0; r < 8; ++r) {
      float k0 = fmaf(-2.f, s[r].x, cn0);
      float k1 = fmaf(-2.f, s[r].y, cn1);
      float k2 = fmaf(-2.f, s[r].z, cn2);
      float k3 = fmaf(-2.f, s[r].w, cn3);
      float v = k0;
      int i = c0;
      if (k1 < v) { v = k1; i = c0 + 1; }
      if (k2 < v) { v = k2; i = c0 + 2; }
      if (k3 < v) { v = k3; i = c0 + 3; }
      bv[r] = v;
      bi[r] = i;
    }
    // wave-level lexicographic-min reduce (64 lanes), all 8 rows
#pragma unroll
    for (int r = 0; r < 8; ++r) {
#pragma unroll
      for (int off = 32; off > 0; off >>= 1) {
        float ov = __shfl_down(bv[r], off);
        int oi = __shfl_down(bi[r], off);
        if (ov < bv[r] || (ov == bv[r] && oi < bi[r])) {
          bv[r] = ov;
          bi[r] = oi;
        }
      }
    }
    if ((t & 63) == 0) {
#pragma unroll
      for (int r = 0; r < 8; ++r) {
        wv[t >> 6][r] = bv[r];
        wis[t >> 6][r] = bi[r];
      }
    }
    __syncthreads();
    if (t < 8) {
      float v = wv[0][t];
      int i = wis[0][t];
#pragma unroll
      for (int k = 1; k < 4; ++k) {
        float ov = wv[k][t];
        int oi = wis[k][t];
        if (ov < v || (ov == v && oi < i)) { v = ov; i = oi; }
      }
      int j = min(b * 8 + t, cnt - 1);
      unsigned long long val =
          ((unsigned long long)orderU32(v) << 32) | (unsigned)i;
      atomicMin(&packed[j], val);
    }
  }
}

// ---------------------------------------------------------------------------
// Resolve flagged rows: idxf[flaglist[j]] = low32(packed[j]). MUST run
// before gather (gather's quant writes overwrite packed's aliased region).
// ---------------------------------------------------------------------------
__global__ void rescore_final_kernel(const int* __restrict__ flaglist,
                                     const int* __restrict__ flagcount,
                                     const unsigned long long* __restrict__ packed,
                                     float* __restrict__ idxf) {
  const int cnt = *flagcount;
  for (int j = blockIdx.x * blockDim.x + threadIdx.x; j < cnt;
       j += gridDim.x * blockDim.x) {
    idxf[flaglist[j]] = (float)(unsigned)(packed[j] & 0xFFFFFFFFull);
  }
}

// ---------------------------------------------------------------------------
// Gather + per-block loss partial + (last block) final loss reduction.
// idxf holds final valid indices by now (rescore_final resolved markers).
// The last finished block runs the EXACT former loss_sum_kernel body
// (same reduction order => bitwise-identical loss). partial/done in d_ws.
// ---------------------------------------------------------------------------
__global__ void gather_loss_kernel(const float* __restrict__ x,
                                   const float* __restrict__ codes,
                                   const float* __restrict__ idxf,
                                   float* __restrict__ quant,
                                   float* __restrict__ partial,
                                   int* __restrict__ done,
                                   float* __restrict__ loss) {
  __shared__ float part[8];
  __shared__ int amLast;
  const int t = threadIdx.x;
  const int wave = t >> 6;
  const int lane = t & 63;
  const int half = lane >> 5;
  const int l = lane & 31;
  const int base = blockIdx.x * 32;

  float s = 0.f;
#pragma unroll
  for (int pass = 0; pass < 4; ++pass) {
    int row = base + pass * 8 + (wave << 1) + half;
    int idx = (int)idxf[row];
    float4 cv = ((const float4*)(codes + (size_t)idx * Dn))[l];
    float4 xv = ((const float4*)(x + (size_t)row * Dn))[l];
    ((float4*)(quant + (size_t)row * Dn))[l] = cv;
    float d0 = xv.x - cv.x, d1 = xv.y - cv.y, d2 = xv.z - cv.z,
          d3 = xv.w - cv.w;
    s += d0 * d0 + d1 * d1 + d2 * d2 + d3 * d3;
  }
#pragma unroll
  for (int off = 16; off > 0; off >>= 1) s += __shfl_down(s, off, 32);
  if (l == 0) part[(wave << 1) + half] = s;
  __syncthreads();
  if (t == 0) {
    float tot = 0.f;
#pragma unroll
    for (int i = 0; i < 8; ++i) tot += part[i];
    partial[blockIdx.x] = tot;
  }
  // Last-block final reduction (bitwise-identical to the old loss_sum).
  __threadfence();
  if (t == 0) amLast = (atomicAdd(done, 1) == (int)gridDim.x - 1);
  __syncthreads();
  if (amLast) {
    __threadfence();
    __shared__ float red[4];
    float ls = 0.f;
    for (int i = t; i < 2048; i += 256) ls += partial[i];
#pragma unroll
    for (int off = 32; off > 0; off >>= 1) ls += __shfl_down(ls, off, 64);
    if ((t & 63) == 0) red[t >> 6] = ls;
    __syncthreads();
    if (t == 0)
      *loss = (red[0] + red[1] + red[2] + red[3]) * (1.25f / 65536.f);
  }
}

// ---------------------------------------------------------------------------
extern "C" void kernel_launch(void* const* d_in, const int* in_sizes, int n_in,
                              void* d_out, int out_size, void* d_ws,
                              size_t ws_size, hipStream_t stream) {
  const float* x = (const float*)d_in[0];
  const float* codes = (const float*)d_in[1];

  float* quant = (float*)d_out;            // B*D floats (scratch until gather)
  float* idxf = quant + (size_t)Bn * Dn;   // B floats
  float* loss = idxf + Bn;                 // 1 float
  float* cnorm = (float*)d_ws;             // 16 KB
  float* partial = cnorm + Cn;             // 8 KB
  int* done = (int*)(partial + 2048);      // 4 B (zeroed by pack_codes)

  _Float16* pack = (_Float16*)quant;           // 1.125 MB @ 0
  int* flagcount = (int*)(quant + (1 << 20));  // @ 4 MB
  int* flaglist = flagcount + 1;               // up to 256 KB
  float* pm1 = quant + (2 << 20);              // @ 8 MB, 1 MB (4 quarters)
  float* pm2 = pm1 + 4 * Bn;                   // @ 9 MB
  float* pidx = pm2 + 4 * Bn;                  // @ 10 MB, ends 11 MB
  float* codesT = quant + (3 << 20);           // @ 12 MB, 2 MB (f32 [D][C])
  unsigned long long* packed =
      (unsigned long long*)(quant + (4 << 20));  // @ 16 MB, <=512 KB
  // NOTE: packed aliases quant rows >= 32768; it is dead before gather runs
  // (rescore_final consumes it) — do not read it after gather starts.

  pack_codes_kernel<<<288, 256, 0, stream>>>(codes, cnorm, pack, codesT,
                                             flagcount, done);
  argmin_mfma_kernel<<<4096, 64, 0, stream>>>(x, pack, pm1, pm2, pidx);
  merge_kernel<<<Bn / 256, 256, 0, stream>>>(pm1, pm2, pidx, idxf, flaglist,
                                             flagcount, packed);
  rescore_part_kernel<<<1024, 256, 0, stream>>>(x, codesT, cnorm, flaglist,
                                                flagcount, packed);
  rescore_final_kernel<<<64, 256, 0, stream>>>(flaglist, flagcount, packed,
                                               idxf);
  gather_loss_kernel<<<Bn / 32, 256, 0, stream>>>(x, codes, idxf, quant,
                                                  partial, done, loss);
}

// Round 14
// 206.570 us; speedup vs baseline: 2.3394x; 2.3394x over previous
//
#include <hip/hip_runtime.h>

constexpr int Bn = 65536;
constexpr int Cn = 4096;
constexpr int Dn = 128;
// Pairwise key-err: x-side f16 std ~3.4e-3 (validated at TAU=0.03, 6 sigma);
// c-side single-f16 => same magnitude, independent => sqrt(2) scale
// (0.042) + u32-mask granularity (~2e-3) + headroom => TAU = 0.055.
// Validated: absmax 0.0 at TAU=0.055 in rounds 3, 5-11, 13.
constexpr float TAU = 0.055f;

typedef _Float16 v8h __attribute__((ext_vector_type(8)));
typedef float v16f __attribute__((ext_vector_type(16)));

#define MFMA16(a, b, c) __builtin_amdgcn_mfma_f32_32x32x16_f16((a), (b), (c), 0, 0, 0)

// ---------------------------------------------------------------------------
// Pack codes into MFMA A-fragment order as SINGLE f16 planes, PRE-SCALED -2.
// Also computes cnorm (fp64) inline, writes a f32 transposed copy codesT[d][c]
// (for the coalesced rescore), and zeroes flagcount.
// Tile ct (128 tiles, 4608 halves = 9216 B):
//   slice s in [0,8): hi @ ct*4608 + s*512 + l*8
//   slice 8: 3-term f16 split of (cnorm[code] + 512) at k=0,1,2 (lanes l<32);
//            with B=ones at k=0..2 one MFMA makes acc = key+512 directly
//            (+512 keeps keys positive => u32-sortable floats).
// ---------------------------------------------------------------------------
__global__ void pack_codes_kernel(const float* __restrict__ codes,
                                  float* __restrict__ cnorm,
                                  _Float16* __restrict__ pack,
                                  float* __restrict__ codesT,
                                  int* __restrict__ flagcount) {
  int tid = blockIdx.x * 256 + threadIdx.x;  // 288 blocks -> 1152 wave-frags
  if (tid == 0) *flagcount = 0;
  int f = tid >> 6;
  int l = tid & 63;
  int ct = f / 9, s = f % 9;
  int code = (ct << 5) + (l & 31);
  if (s < 8) {
    int kb = (s << 4) + ((l >> 5) << 3);
    const float* p = codes + (size_t)code * Dn + kb;
    float4 a = ((const float4*)p)[0];
    float4 b = ((const float4*)p)[1];
    float v[8] = {a.x, a.y, a.z, a.w, b.x, b.y, b.z, b.w};
    // f32 transpose for the rescore path (raw values, no -2 scale)
#pragma unroll
    for (int j = 0; j < 8; ++j)
      codesT[(size_t)(kb + j) * Cn + code] = v[j];
    v8h hi;
#pragma unroll
    for (int j = 0; j < 8; ++j) {
      float sv = -2.f * v[j];  // exact scale
      hi[j] = (_Float16)sv;    // single-term f16 (rescore covers the error)
    }
    *(v8h*)(pack + (size_t)ct * 4608 + s * 512 + l * 8) = hi;
  } else {
    v8h a = {0, 0, 0, 0, 0, 0, 0, 0};
    if (l < 32) {
      const float4* p = (const float4*)(codes + (size_t)code * Dn);
      double sd = 0.0;
#pragma unroll
      for (int i = 0; i < Dn / 4; ++i) {
        float4 v = p[i];
        sd += (double)v.x * v.x + (double)v.y * v.y + (double)v.z * v.z +
              (double)v.w * v.w;
      }
      float cn = (float)sd;
      cnorm[code] = cn;
      float c5 = cn + 512.f;
      _Float16 h1 = (_Float16)c5;
      float r1 = c5 - (float)h1;
      _Float16 h2 = (_Float16)r1;
      float r2 = r1 - (float)h2;
      _Float16 h3 = (_Float16)r2;
      a[0] = h1;
      a[1] = h2;
      a[2] = h3;
    }
    *(v8h*)(pack + (size_t)ct * 4608 + 8 * 512 + l * 8) = a;
  }
}

// ---------------------------------------------------------------------------
// Main: REGISTER-DIRECT code-quarter sweep, within-wave software pipeline.
// (FROZEN at the r10 form — structural floor ~89.5us. Five scheduling
// structures (barriered x3, barrier-free, SWP, SGB-pinned) all landed
// 89-107us with MFMA(31)+VALU(35)+L2(21) adding serially; SGB was null.)
// acc[r] = key + 512 (always positive). Branchless epilogue: pack 4-bit r
// into low mantissa bits; pair-merge network gives exact (min, in-tile 2nd,
// idx) in u32 domain (positive keys => u32 order = f32 order).
// C/D 32x32: col = lane&31 = x-row, code-row = (r&3)+8*(r>>2)+4*(lane>>5).
// ---------------------------------------------------------------------------
__launch_bounds__(64, 2)
__global__ void argmin_mfma_kernel(const float* __restrict__ x,
                                   const _Float16* __restrict__ pack,
                                   float* __restrict__ pm1,
                                   float* __restrict__ pm2,
                                   float* __restrict__ pidx) {
  const int l = threadIdx.x;  // 64-thread block = one wave
  const int h = blockIdx.x & 3;
  const int row0 = (blockIdx.x >> 2) * 64;

  // x fragments -> registers (single f16). Rows row0 + tt*32 + (l&31).
  v8h xh[2][8];
#pragma unroll
  for (int tt = 0; tt < 2; ++tt) {
#pragma unroll
    for (int ks = 0; ks < 8; ++ks) {
      int xrow = row0 + tt * 32 + (l & 31);
      int kb = ks * 16 + (l >> 5) * 8;
      const float* xp = x + (size_t)xrow * Dn + kb;
      float4 a = ((const float4*)xp)[0];
      float4 b = ((const float4*)xp)[1];
      float v[8] = {a.x, a.y, a.z, a.w, b.x, b.y, b.z, b.w};
      v8h hh;
#pragma unroll
      for (int j = 0; j < 8; ++j) hh[j] = (_Float16)v[j];
      xh[tt][ks] = hh;
    }
  }

  // B fragment of f16 ones at k=0,1,2 (pairs with the cnorm A-slice).
  v8h bones;
#pragma unroll
  for (int j = 0; j < 8; ++j)
    bones[j] = (l < 32 && j < 3) ? (_Float16)1.0f : (_Float16)0.0f;

  v16f zacc;
#pragma unroll
  for (int i = 0; i < 16; ++i) zacc[i] = 0.f;

  // Cross-tile state in packed-u32 domain (keys positive).
  unsigned umin1[2] = {0xFFFFFFFFu, 0xFFFFFFFFu};
  unsigned umin2[2] = {0xFFFFFFFFu, 0xFFFFFFFFu};
  int idx[2] = {0, 0};

  auto update = [&](const v16f& a, int tt, int codebase) {
    // pack r into low 4 mantissa bits (values then unique; u32 order = f32)
    unsigned b[16];
#pragma unroll
    for (int r = 0; r < 16; ++r)
      b[r] = (__float_as_uint(a[r]) & 0xFFFFFFF0u) | (unsigned)r;
    // pair-merge network: exact (m1, m2) of 16 values.
    // Invariant: (m1,m2) = two smallest seen; merging sorted pair (lo,hi):
    //   m1' = min(m1,lo); m2' = min(min(m2,hi), max(m1,lo))   [exact]
    unsigned m1 = 0xFFFFFFFFu, m2 = 0xFFFFFFFFu;
#pragma unroll
    for (int i = 0; i < 8; ++i) {
      unsigned lo = min(b[2 * i], b[2 * i + 1]);
      unsigned hi = max(b[2 * i], b[2 * i + 1]);
      unsigned mx = max(m1, lo);
      m1 = min(m1, lo);
      m2 = min(min(m2, hi), mx);
    }
    unsigned r1 = m1 & 15u;
    int tidx = codebase + (int)(8 * (r1 >> 2) + (r1 & 3));
    bool lt = m1 < umin1[tt];
    umin2[tt] = lt ? min(umin1[tt], m2) : min(umin2[tt], m1);
    idx[tt] = lt ? tidx : idx[tt];
    umin1[tt] = lt ? m1 : umin1[tt];
  };

  // Lane-fixed base into this quarter's 32 tiles of A-fragments.
  const _Float16* pb = pack + (size_t)(h * 32) * 4608 + l * 8;

  auto loadf = [&](v8h* f, int it) {
    const _Float16* tp = pb + (size_t)it * 4608;
#pragma unroll
    for (int s = 0; s < 8; ++s) f[s] = *(const v8h*)(tp + s * 512);
    f[8] = *(const v8h*)(tp + 8 * 512);  // cnorm slice
  };

  auto mfma_tile = [&](const v8h* f, v16f& a0, v16f& a1) {
    v16f ini = MFMA16(f[8], bones, zacc);  // ini = cnorm+512 (shared)
    a0 = MFMA16(f[0], xh[0][0], ini);
    a1 = MFMA16(f[0], xh[1][0], ini);
#pragma unroll
    for (int s = 1; s < 8; ++s) {
      a0 = MFMA16(f[s], xh[0][s], a0);
      a1 = MFMA16(f[s], xh[1][s], a1);
    }
  };

  auto cb = [&](int t) { return h * 1024 + t * 32 + 4 * (l >> 5); };

  v8h fA[9], fB[9];
  v16f accA0, accA1, accB0, accB1;

  // Pipeline: prologue fills fA(0), fB(1); steady state computes tile t
  // while updating tile t-1 and prefetching tile t+1.
  loadf(fA, 0);
  loadf(fB, 1);
  mfma_tile(fA, accA0, accA1);  // tile 0
  for (int it = 1; it < 31; it += 2) {
    loadf(fA, it + 1);             // prefetch tile it+1
    mfma_tile(fB, accB0, accB1);   // tile it
    update(accA0, 0, cb(it - 1));  // finish tile it-1 (VALU in MFMA shadow)
    update(accA1, 1, cb(it - 1));
    loadf(fB, it + 2);             // prefetch tile it+2 (max 31)
    mfma_tile(fA, accA0, accA1);   // tile it+1
    update(accB0, 0, cb(it));      // finish tile it
    update(accB1, 1, cb(it));
  }
  mfma_tile(fB, accB0, accB1);  // tile 31
  update(accA0, 0, cb(30));
  update(accA1, 1, cb(30));
  update(accB0, 0, cb(31));
  update(accB1, 1, cb(31));

  // Merge lane pair (l, l^32): same x-row, complementary code rows.
#pragma unroll
  for (int tt = 0; tt < 2; ++tt) {
    unsigned o1 = (unsigned)__shfl_xor((int)umin1[tt], 32);
    unsigned o2 = (unsigned)__shfl_xor((int)umin2[tt], 32);
    int oi = __shfl_xor(idx[tt], 32);
    bool sw = (o1 < umin1[tt]) || (o1 == umin1[tt] && oi < idx[tt]);
    unsigned n1 = sw ? o1 : umin1[tt];
    int ni = sw ? oi : idx[tt];
    unsigned big = sw ? umin1[tt] : o1;
    unsigned n2 = min(min(umin2[tt], o2), big);
    if (l < 32) {
      int row = row0 + tt * 32 + l;
      pm1[h * Bn + row] = __uint_as_float(n1 & 0xFFFFFFF0u);
      pm2[h * Bn + row] = __uint_as_float(n2 & 0xFFFFFFF0u);
      pidx[h * Bn + row] = (float)ni;
    }
  }
}

// ---------------------------------------------------------------------------
// Merge the four code-quarter partials; write idxf; flag small-margin rows.
// Exact: global m2 = min(pm2[h*], min_{h != h*} pm1[h]); sequential insert
// keeps that invariant. Ties prefer lower h (= lower code index).
// Flagged rows get a NEGATIVE marker idxf[r] = -(j+1) pointing at packed[j]
// (init'd to ~0 here); rescore atomicMins it and rescore_final resolves it
// BEFORE gather (packed aliases quant rows >=32768 — gather overwrites it).
// ---------------------------------------------------------------------------
__global__ void merge_kernel(const float* __restrict__ pm1,
                             const float* __restrict__ pm2,
                             const float* __restrict__ pidx,
                             float* __restrict__ idxf,
                             int* __restrict__ flaglist,
                             int* __restrict__ flagcount,
                             unsigned long long* __restrict__ packed) {
  int r = blockIdx.x * 256 + threadIdx.x;
  float m1 = pm1[r];
  float mw2 = pm2[r];  // pm2 of current winner quarter
  float mi = pidx[r];
  float m2 = 3.4e38f;  // min over losers' pm1
#pragma unroll
  for (int h = 1; h < 4; ++h) {
    float v1 = pm1[h * Bn + r];
    float v2 = pm2[h * Bn + r];
    float vi = pidx[h * Bn + r];
    bool win = v1 < m1;
    m2 = fminf(m2, win ? m1 : v1);
    mw2 = win ? v2 : mw2;
    mi = win ? vi : mi;
    m1 = win ? v1 : m1;
  }
  m2 = fminf(m2, mw2);
  if (m2 - m1 < TAU) {
    int p = atomicAdd(flagcount, 1);
    flaglist[p] = r;
    packed[p] = 0xFFFFFFFFFFFFFFFFull;
    idxf[r] = -(float)(p + 1);  // marker: rescore_final resolves it
  } else {
    idxf[r] = mi;
  }
}

// ---------------------------------------------------------------------------
// Exact fp32 rescore, ROW-BATCHED (8 rows share one codesT pass), result via
// per-row u64 atomicMin: val = (orderU32(key) << 32) | idx. orderU32 is the
// standard sign-flip map (order-preserving for ALL floats incl. negatives),
// so u64 min = lexicographic (key asc, idx asc) min — identical selection to
// the old 4-way quarter merge. Clamped tail duplicates are idempotent.
// Per-(row,code) math IDENTICAL to prior rounds => bit-identical keys.
// ---------------------------------------------------------------------------
__device__ __forceinline__ unsigned orderU32(float f) {
  unsigned u = __float_as_uint(f);
  return (u & 0x80000000u) ? ~u : (u | 0x80000000u);
}

__launch_bounds__(256, 4)
__global__ void rescore_part_kernel(const float* __restrict__ x,
                                    const float* __restrict__ codesT,
                                    const float* __restrict__ cnorm,
                                    const int* __restrict__ flaglist,
                                    const int* __restrict__ flagcount,
                                    unsigned long long* __restrict__ packed) {
  __shared__ __align__(16) float xs[8][Dn];
  __shared__ float wv[4][8];
  __shared__ int wis[4][8];
  const int t = threadIdx.x;
  const int cnt = *flagcount;
  const int nb = (cnt + 7) >> 3;
  const int total = nb * 4;

  for (int wi = blockIdx.x; wi < total; wi += gridDim.x) {
    const int b = wi >> 2;
    const int q = wi & 3;
    __syncthreads();  // xs reuse guard (also orders wv/wis reuse)
    {
      int rr = t >> 5;  // 0..7
      int cc = t & 31;  // 0..31
      int j = min(b * 8 + rr, cnt - 1);
      int r = flaglist[j];
      ((float4*)&xs[rr][0])[cc] = ((const float4*)(x + (size_t)r * Dn))[cc];
    }
    __syncthreads();

    const int c0 = q * 1024 + 4 * t;
    const float* cp = codesT + c0;
    float4 s[8];
#pragma unroll
    for (int r = 0; r < 8; ++r) s[r] = (float4){0.f, 0.f, 0.f, 0.f};
    for (int d = 0; d < Dn; ++d) {
      float4 cv = *(const float4*)(cp + (size_t)d * Cn);
#pragma unroll
      for (int r = 0; r < 8; ++r) {
        float xv = xs[r][d];  // LDS broadcast (uniform addr per r)
        s[r].x = fmaf(cv.x, xv, s[r].x);
        s[r].y = fmaf(cv.y, xv, s[r].y);
        s[r].z = fmaf(cv.z, xv, s[r].z);
        s[r].w = fmaf(cv.w, xv, s[r].w);
      }
    }
    const float cn0 = cnorm[c0], cn1 = cnorm[c0 + 1], cn2 = cnorm[c0 + 2],
                cn3 = cnorm[c0 + 3];
    float bv[8];
    int bi[8];
#pragma unroll
    for (int r = 0; r < 8; ++r) {
      float k0 = fmaf(-2.f, s[r].x, cn0);
      float k1 = fmaf(-2.f, s[r].y, cn1);
      float k2 = fmaf(-2.f, s[r].z, cn2);
      float k3 = fmaf(-2.f, s[r].w, cn3);
      float v = k0;
      int i = c0;
      if (k1 < v) { v = k1; i = c0 + 1; }
      if (k2 < v) { v = k2; i = c0 + 2; }
      if (k3 < v) { v = k3; i = c0 + 3; }
      bv[r] = v;
      bi[r] = i;
    }
    // wave-level lexicographic-min reduce (64 lanes), all 8 rows
#pragma unroll
    for (int r = 0; r < 8; ++r) {
#pragma unroll
      for (int off = 32; off > 0; off >>= 1) {
        float ov = __shfl_down(bv[r], off);
        int oi = __shfl_down(bi[r], off);
        if (ov < bv[r] || (ov == bv[r] && oi < bi[r])) {
          bv[r] = ov;
          bi[r] = oi;
        }
      }
    }
    if ((t & 63) == 0) {
#pragma unroll
      for (int r = 0; r < 8; ++r) {
        wv[t >> 6][r] = bv[r];
        wis[t >> 6][r] = bi[r];
      }
    }
    __syncthreads();
    if (t < 8) {
      float v = wv[0][t];
      int i = wis[0][t];
#pragma unroll
      for (int k = 1; k < 4; ++k) {
        float ov = wv[k][t];
        int oi = wis[k][t];
        if (ov < v || (ov == v && oi < i)) { v = ov; i = oi; }
      }
      int j = min(b * 8 + t, cnt - 1);
      unsigned long long val =
          ((unsigned long long)orderU32(v) << 32) | (unsigned)i;
      atomicMin(&packed[j], val);
    }
  }
}

// ---------------------------------------------------------------------------
// Resolve flagged rows: idxf[flaglist[j]] = low32(packed[j]). MUST run
// before gather (gather's quant writes overwrite packed's aliased region).
// ---------------------------------------------------------------------------
__global__ void rescore_final_kernel(const int* __restrict__ flaglist,
                                     const int* __restrict__ flagcount,
                                     const unsigned long long* __restrict__ packed,
                                     float* __restrict__ idxf) {
  const int cnt = *flagcount;
  for (int j = blockIdx.x * blockDim.x + threadIdx.x; j < cnt;
       j += gridDim.x * blockDim.x) {
    idxf[flaglist[j]] = (float)(unsigned)(packed[j] & 0xFFFFFFFFull);
  }
}

// ---------------------------------------------------------------------------
// Gather + per-block loss partial (no global fences — r13's fused last-block
// pattern cost 263us: per-block __threadfence forces device-scope visibility
// across non-coherent XCD L2s, killing store locality. Never fuse this way.)
// ---------------------------------------------------------------------------
__global__ void gather_loss_kernel(const float* __restrict__ x,
                                   const float* __restrict__ codes,
                                   const float* __restrict__ idxf,
                                   float* __restrict__ quant,
                                   float* __restrict__ partial) {
  __shared__ float part[8];
  const int t = threadIdx.x;
  const int wave = t >> 6;
  const int lane = t & 63;
  const int half = lane >> 5;
  const int l = lane & 31;
  const int base = blockIdx.x * 32;

  float s = 0.f;
#pragma unroll
  for (int pass = 0; pass < 4; ++pass) {
    int row = base + pass * 8 + (wave << 1) + half;
    int idx = (int)idxf[row];
    float4 cv = ((const float4*)(codes + (size_t)idx * Dn))[l];
    float4 xv = ((const float4*)(x + (size_t)row * Dn))[l];
    ((float4*)(quant + (size_t)row * Dn))[l] = cv;
    float d0 = xv.x - cv.x, d1 = xv.y - cv.y, d2 = xv.z - cv.z,
          d3 = xv.w - cv.w;
    s += d0 * d0 + d1 * d1 + d2 * d2 + d3 * d3;
  }
#pragma unroll
  for (int off = 16; off > 0; off >>= 1) s += __shfl_down(s, off, 32);
  if (l == 0) part[(wave << 1) + half] = s;
  __syncthreads();
  if (t == 0) {
    float tot = 0.f;
#pragma unroll
    for (int i = 0; i < 8; ++i) tot += part[i];
    partial[blockIdx.x] = tot;
  }
}

// ---------------------------------------------------------------------------
// Final loss reduction: 2048 partials -> loss (direct write, no pre-zero).
// ---------------------------------------------------------------------------
__global__ void loss_sum_kernel(const float* __restrict__ partial,
                                float* __restrict__ loss) {
  __shared__ float red[4];
  const int t = threadIdx.x;
  float s = 0.f;
  for (int i = t; i < 2048; i += 256) s += partial[i];
#pragma unroll
  for (int off = 32; off > 0; off >>= 1) s += __shfl_down(s, off, 64);
  if ((t & 63) == 0) red[t >> 6] = s;
  __syncthreads();
  if (t == 0)
    *loss = (red[0] + red[1] + red[2] + red[3]) * (1.25f / 65536.f);
}

// ---------------------------------------------------------------------------
extern "C" void kernel_launch(void* const* d_in, const int* in_sizes, int n_in,
                              void* d_out, int out_size, void* d_ws,
                              size_t ws_size, hipStream_t stream) {
  const float* x = (const float*)d_in[0];
  const float* codes = (const float*)d_in[1];

  float* quant = (float*)d_out;            // B*D floats (scratch until gather)
  float* idxf = quant + (size_t)Bn * Dn;   // B floats
  float* loss = idxf + Bn;                 // 1 float
  float* cnorm = (float*)d_ws;             // 16 KB
  float* partial = cnorm + Cn;             // 8 KB

  _Float16* pack = (_Float16*)quant;           // 1.125 MB @ 0
  int* flagcount = (int*)(quant + (1 << 20));  // @ 4 MB
  int* flaglist = flagcount + 1;               // up to 256 KB
  float* pm1 = quant + (2 << 20);              // @ 8 MB, 1 MB (4 quarters)
  float* pm2 = pm1 + 4 * Bn;                   // @ 9 MB
  float* pidx = pm2 + 4 * Bn;                  // @ 10 MB, ends 11 MB
  float* codesT = quant + (3 << 20);           // @ 12 MB, 2 MB (f32 [D][C])
  unsigned long long* packed =
      (unsigned long long*)(quant + (4 << 20));  // @ 16 MB, <=512 KB
  // NOTE: packed aliases quant rows >= 32768; it is dead before gather runs
  // (rescore_final consumes it) — do not read it after gather starts.

  pack_codes_kernel<<<288, 256, 0, stream>>>(codes, cnorm, pack, codesT,
                                             flagcount);
  argmin_mfma_kernel<<<4096, 64, 0, stream>>>(x, pack, pm1, pm2, pidx);
  merge_kernel<<<Bn / 256, 256, 0, stream>>>(pm1, pm2, pidx, idxf, flaglist,
                                             flagcount, packed);
  rescore_part_kernel<<<1024, 256, 0, stream>>>(x, codesT, cnorm, flaglist,
                                                flagcount, packed);
  rescore_final_kernel<<<64, 256, 0, stream>>>(flaglist, flagcount, packed,
                                               idxf);
  gather_loss_kernel<<<Bn / 32, 256, 0, stream>>>(x, codes, idxf, quant,
                                                  partial);
  loss_sum_kernel<<<1, 256, 0, stream>>>(partial, loss);
}

// Round 15
// 202.642 us; speedup vs baseline: 2.3848x; 1.0194x over previous
//
#include <hip/hip_runtime.h>

constexpr int Bn = 65536;
constexpr int Cn = 4096;
constexpr int Dn = 128;
// Pairwise key-err: x-side f16 std ~3.4e-3 (validated at TAU=0.03, 6 sigma);
// c-side single-f16 => same magnitude, independent => sqrt(2) scale
// (0.042) + u32-mask granularity (~2e-3) + headroom => TAU = 0.055.
// Validated: absmax 0.0 at TAU=0.055 in rounds 3, 5-11, 13, 14.
constexpr float TAU = 0.055f;

typedef _Float16 v8h __attribute__((ext_vector_type(8)));
typedef float v16f __attribute__((ext_vector_type(16)));

#define MFMA16(a, b, c) __builtin_amdgcn_mfma_f32_32x32x16_f16((a), (b), (c), 0, 0, 0)

// ---------------------------------------------------------------------------
// Pack codes into MFMA A-fragment order as SINGLE f16 planes, PRE-SCALED -2.
// Also computes cnorm (fp64) inline, writes a f32 transposed copy codesT[d][c]
// (for the coalesced rescore), and zeroes flagcount.
// Tile ct (128 tiles, 4608 halves = 9216 B):
//   slice s in [0,8): hi @ ct*4608 + s*512 + l*8
//   slice 8: 3-term f16 split of (cnorm[code] + 512) at k=0,1,2 (lanes l<32);
//            with B=ones at k=0..2 one MFMA makes acc = key+512 directly
//            (+512 keeps keys positive => u32-sortable floats).
// ---------------------------------------------------------------------------
__global__ void pack_codes_kernel(const float* __restrict__ codes,
                                  float* __restrict__ cnorm,
                                  _Float16* __restrict__ pack,
                                  float* __restrict__ codesT,
                                  int* __restrict__ flagcount) {
  int tid = blockIdx.x * 256 + threadIdx.x;  // 288 blocks -> 1152 wave-frags
  if (tid == 0) *flagcount = 0;
  int f = tid >> 6;
  int l = tid & 63;
  int ct = f / 9, s = f % 9;
  int code = (ct << 5) + (l & 31);
  if (s < 8) {
    int kb = (s << 4) + ((l >> 5) << 3);
    const float* p = codes + (size_t)code * Dn + kb;
    float4 a = ((const float4*)p)[0];
    float4 b = ((const float4*)p)[1];
    float v[8] = {a.x, a.y, a.z, a.w, b.x, b.y, b.z, b.w};
    // f32 transpose for the rescore path (raw values, no -2 scale)
#pragma unroll
    for (int j = 0; j < 8; ++j)
      codesT[(size_t)(kb + j) * Cn + code] = v[j];
    v8h hi;
#pragma unroll
    for (int j = 0; j < 8; ++j) {
      float sv = -2.f * v[j];  // exact scale
      hi[j] = (_Float16)sv;    // single-term f16 (rescore covers the error)
    }
    *(v8h*)(pack + (size_t)ct * 4608 + s * 512 + l * 8) = hi;
  } else {
    v8h a = {0, 0, 0, 0, 0, 0, 0, 0};
    if (l < 32) {
      const float4* p = (const float4*)(codes + (size_t)code * Dn);
      double sd = 0.0;
#pragma unroll
      for (int i = 0; i < Dn / 4; ++i) {
        float4 v = p[i];
        sd += (double)v.x * v.x + (double)v.y * v.y + (double)v.z * v.z +
              (double)v.w * v.w;
      }
      float cn = (float)sd;
      cnorm[code] = cn;
      float c5 = cn + 512.f;
      _Float16 h1 = (_Float16)c5;
      float r1 = c5 - (float)h1;
      _Float16 h2 = (_Float16)r1;
      float r2 = r1 - (float)h2;
      _Float16 h3 = (_Float16)r2;
      a[0] = h1;
      a[1] = h2;
      a[2] = h3;
    }
    *(v8h*)(pack + (size_t)ct * 4608 + 8 * 512 + l * 8) = a;
  }
}

// ---------------------------------------------------------------------------
// Main: REGISTER-DIRECT code-quarter sweep, within-wave software pipeline.
// (FROZEN at the r10 form — structural floor ~89.5us. Five scheduling
// structures (barriered x3, barrier-free, SWP, SGB-pinned) all landed
// 89-107us with MFMA(31)+VALU(35)+L2(21) adding serially; SGB was null.)
// acc[r] = key + 512 (always positive). Branchless epilogue: pack 4-bit r
// into low mantissa bits; pair-merge network gives exact (min, in-tile 2nd,
// idx) in u32 domain (positive keys => u32 order = f32 order).
// C/D 32x32: col = lane&31 = x-row, code-row = (r&3)+8*(r>>2)+4*(lane>>5).
// ---------------------------------------------------------------------------
__launch_bounds__(64, 2)
__global__ void argmin_mfma_kernel(const float* __restrict__ x,
                                   const _Float16* __restrict__ pack,
                                   float* __restrict__ pm1,
                                   float* __restrict__ pm2,
                                   float* __restrict__ pidx) {
  const int l = threadIdx.x;  // 64-thread block = one wave
  const int h = blockIdx.x & 3;
  const int row0 = (blockIdx.x >> 2) * 64;

  // x fragments -> registers (single f16). Rows row0 + tt*32 + (l&31).
  v8h xh[2][8];
#pragma unroll
  for (int tt = 0; tt < 2; ++tt) {
#pragma unroll
    for (int ks = 0; ks < 8; ++ks) {
      int xrow = row0 + tt * 32 + (l & 31);
      int kb = ks * 16 + (l >> 5) * 8;
      const float* xp = x + (size_t)xrow * Dn + kb;
      float4 a = ((const float4*)xp)[0];
      float4 b = ((const float4*)xp)[1];
      float v[8] = {a.x, a.y, a.z, a.w, b.x, b.y, b.z, b.w};
      v8h hh;
#pragma unroll
      for (int j = 0; j < 8; ++j) hh[j] = (_Float16)v[j];
      xh[tt][ks] = hh;
    }
  }

  // B fragment of f16 ones at k=0,1,2 (pairs with the cnorm A-slice).
  v8h bones;
#pragma unroll
  for (int j = 0; j < 8; ++j)
    bones[j] = (l < 32 && j < 3) ? (_Float16)1.0f : (_Float16)0.0f;

  v16f zacc;
#pragma unroll
  for (int i = 0; i < 16; ++i) zacc[i] = 0.f;

  // Cross-tile state in packed-u32 domain (keys positive).
  unsigned umin1[2] = {0xFFFFFFFFu, 0xFFFFFFFFu};
  unsigned umin2[2] = {0xFFFFFFFFu, 0xFFFFFFFFu};
  int idx[2] = {0, 0};

  auto update = [&](const v16f& a, int tt, int codebase) {
    // pack r into low 4 mantissa bits (values then unique; u32 order = f32)
    unsigned b[16];
#pragma unroll
    for (int r = 0; r < 16; ++r)
      b[r] = (__float_as_uint(a[r]) & 0xFFFFFFF0u) | (unsigned)r;
    // pair-merge network: exact (m1, m2) of 16 values.
    // Invariant: (m1,m2) = two smallest seen; merging sorted pair (lo,hi):
    //   m1' = min(m1,lo); m2' = min(min(m2,hi), max(m1,lo))   [exact]
    unsigned m1 = 0xFFFFFFFFu, m2 = 0xFFFFFFFFu;
#pragma unroll
    for (int i = 0; i < 8; ++i) {
      unsigned lo = min(b[2 * i], b[2 * i + 1]);
      unsigned hi = max(b[2 * i], b[2 * i + 1]);
      unsigned mx = max(m1, lo);
      m1 = min(m1, lo);
      m2 = min(min(m2, hi), mx);
    }
    unsigned r1 = m1 & 15u;
    int tidx = codebase + (int)(8 * (r1 >> 2) + (r1 & 3));
    bool lt = m1 < umin1[tt];
    umin2[tt] = lt ? min(umin1[tt], m2) : min(umin2[tt], m1);
    idx[tt] = lt ? tidx : idx[tt];
    umin1[tt] = lt ? m1 : umin1[tt];
  };

  // Lane-fixed base into this quarter's 32 tiles of A-fragments.
  const _Float16* pb = pack + (size_t)(h * 32) * 4608 + l * 8;

  auto loadf = [&](v8h* f, int it) {
    const _Float16* tp = pb + (size_t)it * 4608;
#pragma unroll
    for (int s = 0; s < 8; ++s) f[s] = *(const v8h*)(tp + s * 512);
    f[8] = *(const v8h*)(tp + 8 * 512);  // cnorm slice
  };

  auto mfma_tile = [&](const v8h* f, v16f& a0, v16f& a1) {
    v16f ini = MFMA16(f[8], bones, zacc);  // ini = cnorm+512 (shared)
    a0 = MFMA16(f[0], xh[0][0], ini);
    a1 = MFMA16(f[0], xh[1][0], ini);
#pragma unroll
    for (int s = 1; s < 8; ++s) {
      a0 = MFMA16(f[s], xh[0][s], a0);
      a1 = MFMA16(f[s], xh[1][s], a1);
    }
  };

  auto cb = [&](int t) { return h * 1024 + t * 32 + 4 * (l >> 5); };

  v8h fA[9], fB[9];
  v16f accA0, accA1, accB0, accB1;

  // Pipeline: prologue fills fA(0), fB(1); steady state computes tile t
  // while updating tile t-1 and prefetching tile t+1.
  loadf(fA, 0);
  loadf(fB, 1);
  mfma_tile(fA, accA0, accA1);  // tile 0
  for (int it = 1; it < 31; it += 2) {
    loadf(fA, it + 1);             // prefetch tile it+1
    mfma_tile(fB, accB0, accB1);   // tile it
    update(accA0, 0, cb(it - 1));  // finish tile it-1 (VALU in MFMA shadow)
    update(accA1, 1, cb(it - 1));
    loadf(fB, it + 2);             // prefetch tile it+2 (max 31)
    mfma_tile(fA, accA0, accA1);   // tile it+1
    update(accB0, 0, cb(it));      // finish tile it
    update(accB1, 1, cb(it));
  }
  mfma_tile(fB, accB0, accB1);  // tile 31
  update(accA0, 0, cb(30));
  update(accA1, 1, cb(30));
  update(accB0, 0, cb(31));
  update(accB1, 1, cb(31));

  // Merge lane pair (l, l^32): same x-row, complementary code rows.
#pragma unroll
  for (int tt = 0; tt < 2; ++tt) {
    unsigned o1 = (unsigned)__shfl_xor((int)umin1[tt], 32);
    unsigned o2 = (unsigned)__shfl_xor((int)umin2[tt], 32);
    int oi = __shfl_xor(idx[tt], 32);
    bool sw = (o1 < umin1[tt]) || (o1 == umin1[tt] && oi < idx[tt]);
    unsigned n1 = sw ? o1 : umin1[tt];
    int ni = sw ? oi : idx[tt];
    unsigned big = sw ? umin1[tt] : o1;
    unsigned n2 = min(min(umin2[tt], o2), big);
    if (l < 32) {
      int row = row0 + tt * 32 + l;
      pm1[h * Bn + row] = __uint_as_float(n1 & 0xFFFFFFF0u);
      pm2[h * Bn + row] = __uint_as_float(n2 & 0xFFFFFFF0u);
      pidx[h * Bn + row] = (float)ni;
    }
  }
}

// ---------------------------------------------------------------------------
// Merge the four code-quarter partials; write idxf; flag small-margin rows.
// Exact: global m2 = min(pm2[h*], min_{h != h*} pm1[h]); sequential insert
// keeps that invariant. Ties prefer lower h (= lower code index).
// Flagged rows get a NEGATIVE marker idxf[r] = -(j+1) pointing at packed[j]
// (init'd to ~0 here); rescore atomicMins it; either rescore_final (aliased
// path) or gather itself (workspace path) resolves the marker.
// ---------------------------------------------------------------------------
__global__ void merge_kernel(const float* __restrict__ pm1,
                             const float* __restrict__ pm2,
                             const float* __restrict__ pidx,
                             float* __restrict__ idxf,
                             int* __restrict__ flaglist,
                             int* __restrict__ flagcount,
                             unsigned long long* __restrict__ packed) {
  int r = blockIdx.x * 256 + threadIdx.x;
  float m1 = pm1[r];
  float mw2 = pm2[r];  // pm2 of current winner quarter
  float mi = pidx[r];
  float m2 = 3.4e38f;  // min over losers' pm1
#pragma unroll
  for (int h = 1; h < 4; ++h) {
    float v1 = pm1[h * Bn + r];
    float v2 = pm2[h * Bn + r];
    float vi = pidx[h * Bn + r];
    bool win = v1 < m1;
    m2 = fminf(m2, win ? m1 : v1);
    mw2 = win ? v2 : mw2;
    mi = win ? vi : mi;
    m1 = win ? v1 : m1;
  }
  m2 = fminf(m2, mw2);
  if (m2 - m1 < TAU) {
    int p = atomicAdd(flagcount, 1);
    flaglist[p] = r;
    packed[p] = 0xFFFFFFFFFFFFFFFFull;
    idxf[r] = -(float)(p + 1);  // marker
  } else {
    idxf[r] = mi;
  }
}

// ---------------------------------------------------------------------------
// Exact fp32 rescore, ROW-BATCHED (8 rows share one codesT pass), result via
// per-row u64 atomicMin: val = (orderU32(key) << 32) | idx. orderU32 is the
// standard sign-flip map (order-preserving for ALL floats incl. negatives),
// so u64 min = lexicographic (key asc, idx asc) min — identical selection to
// the old 4-way quarter merge. Clamped tail duplicates are idempotent.
// Per-(row,code) math IDENTICAL to prior rounds => bit-identical keys.
// ---------------------------------------------------------------------------
__device__ __forceinline__ unsigned orderU32(float f) {
  unsigned u = __float_as_uint(f);
  return (u & 0x80000000u) ? ~u : (u | 0x80000000u);
}

__launch_bounds__(256, 4)
__global__ void rescore_part_kernel(const float* __restrict__ x,
                                    const float* __restrict__ codesT,
                                    const float* __restrict__ cnorm,
                                    const int* __restrict__ flaglist,
                                    const int* __restrict__ flagcount,
                                    unsigned long long* __restrict__ packed) {
  __shared__ __align__(16) float xs[8][Dn];
  __shared__ float wv[4][8];
  __shared__ int wis[4][8];
  const int t = threadIdx.x;
  const int cnt = *flagcount;
  const int nb = (cnt + 7) >> 3;
  const int total = nb * 4;

  for (int wi = blockIdx.x; wi < total; wi += gridDim.x) {
    const int b = wi >> 2;
    const int q = wi & 3;
    __syncthreads();  // xs reuse guard (also orders wv/wis reuse)
    {
      int rr = t >> 5;  // 0..7
      int cc = t & 31;  // 0..31
      int j = min(b * 8 + rr, cnt - 1);
      int r = flaglist[j];
      ((float4*)&xs[rr][0])[cc] = ((const float4*)(x + (size_t)r * Dn))[cc];
    }
    __syncthreads();

    const int c0 = q * 1024 + 4 * t;
    const float* cp = codesT + c0;
    float4 s[8];
#pragma unroll
    for (int r = 0; r < 8; ++r) s[r] = (float4){0.f, 0.f, 0.f, 0.f};
    for (int d = 0; d < Dn; ++d) {
      float4 cv = *(const float4*)(cp + (size_t)d * Cn);
#pragma unroll
      for (int r = 0; r < 8; ++r) {
        float xv = xs[r][d];  // LDS broadcast (uniform addr per r)
        s[r].x = fmaf(cv.x, xv, s[r].x);
        s[r].y = fmaf(cv.y, xv, s[r].y);
        s[r].z = fmaf(cv.z, xv, s[r].z);
        s[r].w = fmaf(cv.w, xv, s[r].w);
      }
    }
    const float cn0 = cnorm[c0], cn1 = cnorm[c0 + 1], cn2 = cnorm[c0 + 2],
                cn3 = cnorm[c0 + 3];
    float bv[8];
    int bi[8];
#pragma unroll
    for (int r = 0; r < 8; ++r) {
      float k0 = fmaf(-2.f, s[r].x, cn0);
      float k1 = fmaf(-2.f, s[r].y, cn1);
      float k2 = fmaf(-2.f, s[r].z, cn2);
      float k3 = fmaf(-2.f, s[r].w, cn3);
      float v = k0;
      int i = c0;
      if (k1 < v) { v = k1; i = c0 + 1; }
      if (k2 < v) { v = k2; i = c0 + 2; }
      if (k3 < v) { v = k3; i = c0 + 3; }
      bv[r] = v;
      bi[r] = i;
    }
    // wave-level lexicographic-min reduce (64 lanes), all 8 rows
#pragma unroll
    for (int r = 0; r < 8; ++r) {
#pragma unroll
      for (int off = 32; off > 0; off >>= 1) {
        float ov = __shfl_down(bv[r], off);
        int oi = __shfl_down(bi[r], off);
        if (ov < bv[r] || (ov == bv[r] && oi < bi[r])) {
          bv[r] = ov;
          bi[r] = oi;
        }
      }
    }
    if ((t & 63) == 0) {
#pragma unroll
      for (int r = 0; r < 8; ++r) {
        wv[t >> 6][r] = bv[r];
        wis[t >> 6][r] = bi[r];
      }
    }
    __syncthreads();
    if (t < 8) {
      float v = wv[0][t];
      int i = wis[0][t];
#pragma unroll
      for (int k = 1; k < 4; ++k) {
        float ov = wv[k][t];
        int oi = wis[k][t];
        if (ov < v || (ov == v && oi < i)) { v = ov; i = oi; }
      }
      int j = min(b * 8 + t, cnt - 1);
      unsigned long long val =
          ((unsigned long long)orderU32(v) << 32) | (unsigned)i;
      atomicMin(&packed[j], val);
    }
  }
}

// ---------------------------------------------------------------------------
// Resolve flagged rows: idxf[flaglist[j]] = low32(packed[j]). Used ONLY in
// the aliased-packed fallback path (packed inside quant): must run before
// gather overwrites that region. In the workspace path gather resolves
// markers itself and this kernel is not launched.
// ---------------------------------------------------------------------------
__global__ void rescore_final_kernel(const int* __restrict__ flaglist,
                                     const int* __restrict__ flagcount,
                                     const unsigned long long* __restrict__ packed,
                                     float* __restrict__ idxf) {
  const int cnt = *flagcount;
  for (int j = blockIdx.x * blockDim.x + threadIdx.x; j < cnt;
       j += gridDim.x * blockDim.x) {
    idxf[flaglist[j]] = (float)(unsigned)(packed[j] & 0xFFFFFFFFull);
  }
}

// ---------------------------------------------------------------------------
// Gather + per-block loss partial. Rows with a negative idxf marker resolve
// their final index from packed[] (workspace path only — packed is then in
// d_ws, NOT aliased with quant; stream ordering makes rescore's atomicMin
// results visible, no fences needed). In the fallback path no markers
// remain, so packed is never read. (No device fences anywhere — r13's
// fused last-block pattern cost 263us via per-block __threadfence.)
// ---------------------------------------------------------------------------
__global__ void gather_loss_kernel(const float* __restrict__ x,
                                   const float* __restrict__ codes,
                                   float* __restrict__ idxf,
                                   const unsigned long long* __restrict__ packed,
                                   float* __restrict__ quant,
                                   float* __restrict__ partial) {
  __shared__ float part[8];
  const int t = threadIdx.x;
  const int wave = t >> 6;
  const int lane = t & 63;
  const int half = lane >> 5;
  const int l = lane & 31;
  const int base = blockIdx.x * 32;

  float s = 0.f;
#pragma unroll
  for (int pass = 0; pass < 4; ++pass) {
    int row = base + pass * 8 + (wave << 1) + half;
    float fi = idxf[row];
    int idx;
    if (fi < 0.f) {
      int j = (int)(-fi) - 1;
      idx = (int)(unsigned)(packed[j] & 0xFFFFFFFFull);
      if (l == 0) idxf[row] = (float)idx;  // finalize output index
    } else {
      idx = (int)fi;
    }
    float4 cv = ((const float4*)(codes + (size_t)idx * Dn))[l];
    float4 xv = ((const float4*)(x + (size_t)row * Dn))[l];
    ((float4*)(quant + (size_t)row * Dn))[l] = cv;
    float d0 = xv.x - cv.x, d1 = xv.y - cv.y, d2 = xv.z - cv.z,
          d3 = xv.w - cv.w;
    s += d0 * d0 + d1 * d1 + d2 * d2 + d3 * d3;
  }
#pragma unroll
  for (int off = 16; off > 0; off >>= 1) s += __shfl_down(s, off, 32);
  if (l == 0) part[(wave << 1) + half] = s;
  __syncthreads();
  if (t == 0) {
    float tot = 0.f;
#pragma unroll
    for (int i = 0; i < 8; ++i) tot += part[i];
    partial[blockIdx.x] = tot;
  }
}

// ---------------------------------------------------------------------------
// Final loss reduction: 2048 partials -> loss (direct write, no pre-zero).
// ---------------------------------------------------------------------------
__global__ void loss_sum_kernel(const float* __restrict__ partial,
                                float* __restrict__ loss) {
  __shared__ float red[4];
  const int t = threadIdx.x;
  float s = 0.f;
  for (int i = t; i < 2048; i += 256) s += partial[i];
#pragma unroll
  for (int off = 32; off > 0; off >>= 1) s += __shfl_down(s, off, 64);
  if ((t & 63) == 0) red[t >> 6] = s;
  __syncthreads();
  if (t == 0)
    *loss = (red[0] + red[1] + red[2] + red[3]) * (1.25f / 65536.f);
}

// ---------------------------------------------------------------------------
extern "C" void kernel_launch(void* const* d_in, const int* in_sizes, int n_in,
                              void* d_out, int out_size, void* d_ws,
                              size_t ws_size, hipStream_t stream) {
  const float* x = (const float*)d_in[0];
  const float* codes = (const float*)d_in[1];

  float* quant = (float*)d_out;            // B*D floats (scratch until gather)
  float* idxf = quant + (size_t)Bn * Dn;   // B floats
  float* loss = idxf + Bn;                 // 1 float
  float* cnorm = (float*)d_ws;             // 16 KB
  float* partial = cnorm + Cn;             // 8 KB

  _Float16* pack = (_Float16*)quant;           // 1.125 MB @ 0
  int* flagcount = (int*)(quant + (1 << 20));  // @ 4 MB
  int* flaglist = flagcount + 1;               // up to 256 KB
  float* pm1 = quant + (2 << 20);              // @ 8 MB, 1 MB (4 quarters)
  float* pm2 = pm1 + 4 * Bn;                   // @ 9 MB
  float* pidx = pm2 + 4 * Bn;                  // @ 10 MB, ends 11 MB
  float* codesT = quant + (3 << 20);           // @ 12 MB, 2 MB (f32 [D][C])

  // packed[]: worst case Bn rows flagged = 512 KB. Prefer workspace (not
  // aliased with quant => gather can resolve markers itself, saving the
  // rescore_final launch). Fallback: alias quant @16MB + rescore_final.
  const bool ws_big = ws_size >= (size_t)(640 << 10);
  unsigned long long* packed =
      ws_big ? (unsigned long long*)((char*)d_ws + (64 << 10))
             : (unsigned long long*)(quant + (4 << 20));

  pack_codes_kernel<<<288, 256, 0, stream>>>(codes, cnorm, pack, codesT,
                                             flagcount);
  argmin_mfma_kernel<<<4096, 64, 0, stream>>>(x, pack, pm1, pm2, pidx);
  merge_kernel<<<Bn / 256, 256, 0, stream>>>(pm1, pm2, pidx, idxf, flaglist,
                                             flagcount, packed);
  rescore_part_kernel<<<1024, 256, 0, stream>>>(x, codesT, cnorm, flaglist,
                                                flagcount, packed);
  if (!ws_big) {
    // Aliased path: resolve markers before gather overwrites packed's region.
    rescore_final_kernel<<<64, 256, 0, stream>>>(flaglist, flagcount, packed,
                                                 idxf);
  }
  gather_loss_kernel<<<Bn / 32, 256, 0, stream>>>(x, codes, idxf, packed,
                                                  quant, partial);
  loss_sum_kernel<<<1, 256, 0, stream>>>(partial, loss);
}